// Round 7
// baseline (54.425 us; speedup 1.0000x reference)
//
#include <hip/hip_runtime.h>

// NormalizingFlow: 4 layers of monotonic linear-rational splines (pyro-style),
// B=262144 rows, D=64 dims, K=8 bins.
//
// Each spline sub-piece (bin x lambda-half) is a Mobius map f(x)=(Ax+B)/(Cx+D);
// Mobius maps compose, so the 4-layer chain per dim is piecewise-Mobius with
// <= 61 pieces. Fused precompute builds per-(d,piece) det-normalized (det=1)
// ABSOLUTE coefficient matrices; main kernel: 2-level search (coarse knots in
// registers, fine knots via L1-resident GLOBAL gathers) + one LDS coeff gather
// + Mobius. lad = -2*ln|den| (det==1). LDS holds ONLY the 61KB coeff table so
// two 1024-thread blocks co-schedule per CU (32 waves). DPP wave reduce.

#define BATCH 262144
#define DIM   64
#define NLAY  4
#define NK    8

// float offsets in d_ws (units: floats from base)
#define OFF_KN0 0       // [8][64][4] fine knots bnd[8c+0..3] (slot0 unused)
#define OFF_KN1 2048    // [8][64][4] fine knots bnd[8c+4..7]
#define OFF_CRS 4096    // [7][64] coarse knots bnd[8],bnd[16],...,bnd[56]
#define OFF_CF0 4544    // [61][64][4] piece coeffs (A,B,C,D) det-normalized

// Fused precompute: one block per dim d (64 blocks x 64 threads).
// Phase 1 parallelized over 32 threads: t = l*8 + k (layer l, bin k); each
// thread replicates the serial softmax-prefix rounding for its own bin.
__global__ void nf_pre(const float* __restrict__ uw, const float* __restrict__ uh,
                       const float* __restrict__ ud, const float* __restrict__ ul,
                       float* __restrict__ F) {
  __shared__ double Lb[NLAY][17], Ly[NLAY][17], LM[NLAY][16][4], Ld[NLAY][16];
  __shared__ double sx[64], Fb[65];
  int d = blockIdx.x;
  int t = threadIdx.x;

  if (t < 32) {
    int l = t >> 3, k = t & 7;
    const float* pw  = uw + (l*DIM + d)*NK;
    const float* ph  = uh + (l*DIM + d)*NK;
    const float* pdv = ud + (l*DIM + d)*(NK-1);
    const float* pl  = ul + (l*DIM + d)*NK;

    // widths softmax (serial-order rounding preserved)
    float ev[NK];
    float mw = pw[0];
    for (int j = 1; j < NK; ++j) mw = fmaxf(mw, pw[j]);
    float sw = 0.f;
    for (int j = 0; j < NK; ++j) { ev[j] = expf(pw[j] - mw); sw += ev[j]; }
    float invw = 1.f / sw;
    float cwe = 0.f, cwi = 0.f;
    for (int j = 0; j <= k; ++j) {
      float vj = 1e-3f + (1.f - 1e-3f * (float)NK) * (ev[j] * invw);
      cwe = cwi; cwi += vj;
    }
    float kwL = (k == 0) ? -3.f : 6.f * cwe - 3.f;
    float kwR = (k == 7) ?  3.f : 6.f * cwi - 3.f;
    float wwk = kwR - kwL;

    // heights softmax
    float mh = ph[0];
    for (int j = 1; j < NK; ++j) mh = fmaxf(mh, ph[j]);
    float sh = 0.f;
    for (int j = 0; j < NK; ++j) { ev[j] = expf(ph[j] - mh); sh += ev[j]; }
    float invh = 1.f / sh;
    float che = 0.f, chi = 0.f;
    for (int j = 0; j <= k; ++j) {
      float vj = 1e-3f + (1.f - 1e-3f * (float)NK) * (ev[j] * invh);
      che = chi; chi += vj;
    }
    float khL = (k == 0) ? -3.f : 6.f * che - 3.f;
    float khR = (k == 7) ?  3.f : 6.f * chi - 3.f;
    float hhk = khR - khL;

    // derivatives at both ends of bin k; lambda
    float dvk, dvk1;
    if (k == 0) dvk = 1.f;
    else { float u = pdv[k-1]; dvk  = 1e-3f + (fmaxf(u,0.f) + log1pf(expf(-fabsf(u)))); }
    if (k == 7) dvk1 = 1.f;
    else { float u = pdv[k];   dvk1 = 1e-3f + (fmaxf(u,0.f) + log1pf(expf(-fabsf(u)))); }
    float sg = 1.f / (1.f + expf(-pl[k]));
    float lmk = 0.95f * sg + 0.025f;

    float delta = hhk / wwk;
    float wbf = sqrtf(dvk / dvk1);
    float wcf = (lmk*dvk + (1.f-lmk)*wbf*dvk1) / delta;
    float yaf = khL, ybf = hhk + khL;
    float ycf = ((1.f-lmk)*yaf + lmk*wbf*ybf) / ((1.f-lmk) + lmk*wbf);

    if (k == 0) {
      Lb[l][0] = -3.0; Lb[l][16] = 3.0;
      Ly[l][0] = -3.0; Ly[l][16] = 3.0;
    }
    if (k) Lb[l][2*k] = (double)(kwL + 1.0e-6f);   // bin boundary (fp32 +EPS)
    Lb[l][2*k+1] = (double)kwL + (double)lmk*(double)wwk;  // theta==lambda
    Ly[l][2*k]   = (double)yaf;
    Ly[l][2*k+1] = (double)ycf;

    double icw = (double)kwL, iw = (double)wwk, il = (double)lmk;
    double wb = wbf, wc = wcf, ya = yaf, yb = ybf, yc = ycf;
    double n0 = ya*il, n1 = wc*yc - ya, d0 = il, d1 = wc - 1.0;
    double A = n1, Bv = n0*iw - n1*icw, C = d1, Dv = d0*iw - d1*icw;
    LM[l][2*k][0]=A; LM[l][2*k][1]=Bv; LM[l][2*k][2]=C; LM[l][2*k][3]=Dv;
    Ld[l][2*k] = log2(A*Dv - Bv*C);
    n0 = wc*yc - il*wb*yb; n1 = wb*yb - wc*yc; d0 = wc - il*wb; d1 = wb - wc;
    A = n1; Bv = n0*iw - n1*icw; C = d1; Dv = d0*iw - d1*icw;
    LM[l][2*k+1][0]=A; LM[l][2*k+1][1]=Bv; LM[l][2*k+1][2]=C; LM[l][2*k+1][3]=Dv;
    Ld[l][2*k+1] = log2(A*Dv - Bv*C);
  }
  __syncthreads();

  if (t < 60) {
    int lp  = t / 15;
    int mth = t % 15 + 1;
    double x = Lb[lp][mth];
    for (int q = lp - 1; q >= 0; --q) {
      int j = 0;
      for (int k = 1; k <= 15; ++k) j += (x >= Ly[q][k]) ? 1 : 0;
      const double* M = LM[q][j];
      x = (M[3]*x - M[1]) / (M[0] - M[2]*x);  // Mobius inverse
    }
    sx[t] = x;
  }
  __syncthreads();
  if (t < 60) {
    double x = sx[t];
    int r = 0;
    for (int s2 = 0; s2 < 60; ++s2) {
      double o = sx[s2];
      r += (o < x || (o == x && s2 < t)) ? 1 : 0;
    }
    Fb[r+1] = x;
  }
  if (t == 0)  Fb[0] = -3.0;
  if (t >= 60) Fb[t+1] = 3.0;   // Fb[61..64] geometry pads
  __syncthreads();

  // fp32 search tables
  {
    int j = t;
    float bf;
    if (j == 0)       bf = -3.0f;
    else if (j <= 60) bf = (float)Fb[j];
    else              bf = 1e30f;         // pads: never counted
    int cw = j >> 3, r8 = j & 7;
    if (r8 < 4) F[OFF_KN0 + (cw*DIM + d)*4 + r8]     = bf;
    else        F[OFF_KN1 + (cw*DIM + d)*4 + (r8-4)] = bf;
    if (j >= 8 && (j & 7) == 0 && j <= 56) F[OFF_CRS + (j/8 - 1)*DIM + d] = bf;
  }

  // per-piece composed ABSOLUTE coefficients (no recentering), det -> 1
  if (t < 61) {
    int p = t;
    double bl = Fb[p], br = Fb[p+1];
    float xmf = (float)(0.5*(bl+br));
    xmf = fminf(fmaxf(xmf, -3.f), 3.f);
    double y = (double)xmf;
    double A=1.0, Bv=0.0, C=0.0, Dv=1.0, ld2 = 0.0;
    for (int q = 0; q < NLAY; ++q) {
      int j = 0;
      for (int k = 1; k <= 15; ++k) j += (y >= Lb[q][k]) ? 1 : 0;
      const double* M = LM[q][j];
      ld2 += Ld[q][j];
      double A2 = M[0]*A + M[1]*C, B2 = M[0]*Bv + M[1]*Dv;
      double C2 = M[2]*A + M[3]*C, D2 = M[2]*Bv + M[3]*Dv;
      y = (M[0]*y + M[1]) / (M[2]*y + M[3]);
      A=A2; Bv=B2; C=C2; Dv=D2;
    }
    double sinv = exp2(-0.5 * ld2);              // det -> 1
    float4 c4;
    c4.x = (float)(A*sinv); c4.y = (float)(Bv*sinv);
    c4.z = (float)(C*sinv); c4.w = (float)(Dv*sinv);
    *(float4*)(F + OFF_CF0 + (size_t)(p*DIM + d)*4) = c4;
  }
}

template <int CTRL>
__device__ __forceinline__ float dpp_add(float x) {
  int yi = __builtin_amdgcn_update_dpp(0, __float_as_int(x), CTRL, 0xF, 0xF, false);
  return x + __int_as_float(yi);
}
// wave64 sum -> lane 63 (rocPRIM gfx9 sequence)
__device__ __forceinline__ float wave_sum63(float x) {
  x = dpp_add<0x111>(x);  // row_shr:1
  x = dpp_add<0x112>(x);  // row_shr:2
  x = dpp_add<0x114>(x);  // row_shr:4
  x = dpp_add<0x118>(x);  // row_shr:8
  x = dpp_add<0x142>(x);  // row_bcast:15
  x = dpp_add<0x143>(x);  // row_bcast:31
  return x;
}

// Main: lane = dim; wave owns 32 rows as 16 units of 2, software-pipelined:
//   R1: coarse(unit k+1) + issue fine-knot GLOBAL loads (L1-hit) + X prefetch
//   R2: math(unit k) with coeffs read LAST iteration
//   R3: fine-search(unit k+1) + issue LDS coeff reads
// LDS = coeff table only (62464 B) -> 2 blocks/CU -> 32 waves/CU.
__global__ __launch_bounds__(1024, 8) void nf_main(const float* __restrict__ X,
                                                   const float* __restrict__ F,
                                                   float* __restrict__ OUT,
                                                   float* __restrict__ LDo) {
  __shared__ float smem[15616];   // [61][64][4] floats = 62464 B
  int t = threadIdx.x;
  {
    float4* dst = (float4*)smem;
    const float4* ct = (const float4*)(F + OFF_CF0);
    for (int i = t; i < 3904; i += 1024) dst[i] = ct[i];
  }
  int d = t & 63;
  float k1 = F[OFF_CRS + 0*DIM + d];
  float k2 = F[OFF_CRS + 1*DIM + d];
  float k3 = F[OFF_CRS + 2*DIM + d];
  float k4 = F[OFF_CRS + 3*DIM + d];
  float k5 = F[OFF_CRS + 4*DIM + d];
  float k6 = F[OFF_CRS + 5*DIM + d];
  float k7 = F[OFF_CRS + 6*DIM + d];
  __syncthreads();
  const float4* skv = (const float4*)smem;
  const float4* KT0 = (const float4*)(F + OFF_KN0);
  const float4* KT1 = (const float4*)(F + OFF_KN1);

  int gw = blockIdx.x * 16 + (t >> 6);          // 0..8191; wave owns 32 rows
  const float* Xb = X   + (size_t)gw*32*DIM + d;
  float*       Ob = OUT + (size_t)gw*32*DIM + d;
  float*       Lp = LDo + (size_t)gw*32;

#define COARSE(xc) ((xc>=k1)+(xc>=k2)+(xc>=k3)+(xc>=k4)+(xc>=k5)+(xc>=k6)+(xc>=k7))
#define FINE(xc, cc, f0, f1) \
  ((cc<<3) + (int)(xc>=f0.y)+(int)(xc>=f0.z)+(int)(xc>=f0.w)+(int)(xc>=f1.x) \
           + (int)(xc>=f1.y)+(int)(xc>=f1.z)+(int)(xc>=f1.w))

  // ---- prologue: full search of unit 0; load x of unit 1 ----
  float xA0 = Xb[0], xA1 = Xb[64];
  float xB0 = Xb[128], xB1 = Xb[192];
  float xcA0 = fminf(fmaxf(xA0, -3.f), 3.f);
  float xcA1 = fminf(fmaxf(xA1, -3.f), 3.f);
  float4 cfA0, cfA1;
  {
    int c0 = COARSE(xcA0), c1 = COARSE(xcA1);
    float4 f00 = KT0[(c0<<6)+d], f01 = KT1[(c0<<6)+d];
    float4 f10 = KT0[(c1<<6)+d], f11 = KT1[(c1<<6)+d];
    int p0 = FINE(xcA0, c0, f00, f01);
    int p1 = FINE(xcA1, c1, f10, f11);
    cfA0 = skv[(p0<<6)+d];
    cfA1 = skv[(p1<<6)+d];
  }

  for (int it = 0; it < 15; ++it) {
    // ---- R1: coarse(unit it+1), issue fine loads; prefetch x(unit it+2) ----
    float xcB0 = fminf(fmaxf(xB0, -3.f), 3.f);
    float xcB1 = fminf(fmaxf(xB1, -3.f), 3.f);
    int cB0 = COARSE(xcB0), cB1 = COARSE(xcB1);
    float4 f00 = KT0[(cB0<<6)+d], f01 = KT1[(cB0<<6)+d];
    float4 f10 = KT0[(cB1<<6)+d], f11 = KT1[(cB1<<6)+d];
    int u2 = (it < 14) ? (it + 2) : 15;
    float xF0 = Xb[u2*128], xF1 = Xb[u2*128 + 64];
    __builtin_amdgcn_sched_barrier(0);
    // ---- R2: math(unit it) using cfA (read last iteration) ----
    float num0 = fmaf(cfA0.x, xcA0, cfA0.y);
    float den0 = fmaf(cfA0.z, xcA0, cfA0.w);
    float o0 = (xA0 == xcA0) ? __fdividef(num0, den0) : xA0;
    float l0 = -1.3862943611198906f * __log2f(fabsf(den0));
    float num1 = fmaf(cfA1.x, xcA1, cfA1.y);
    float den1 = fmaf(cfA1.z, xcA1, cfA1.w);
    float o1 = (xA1 == xcA1) ? __fdividef(num1, den1) : xA1;
    float l1 = -1.3862943611198906f * __log2f(fabsf(den1));
    Ob[it*128] = o0; Ob[it*128 + 64] = o1;
    float s0 = wave_sum63(l0);
    float s1 = wave_sum63(l1);
    if (d == 63) {
      float2 v; v.x = s0; v.y = s1;
      *(float2*)(Lp + 2*it) = v;
    }
    __builtin_amdgcn_sched_barrier(0);
    // ---- R3: fine-search(unit it+1) + issue coeff reads ----
    int p0 = FINE(xcB0, cB0, f00, f01);
    int p1 = FINE(xcB1, cB1, f10, f11);
    cfA0 = skv[(p0<<6)+d];
    cfA1 = skv[(p1<<6)+d];
    xA0 = xB0; xA1 = xB1; xcA0 = xcB0; xcA1 = xcB1;
    xB0 = xF0; xB1 = xF1;
  }
  // ---- epilogue: math(unit 15) ----
  {
    float num0 = fmaf(cfA0.x, xcA0, cfA0.y);
    float den0 = fmaf(cfA0.z, xcA0, cfA0.w);
    float o0 = (xA0 == xcA0) ? __fdividef(num0, den0) : xA0;
    float l0 = -1.3862943611198906f * __log2f(fabsf(den0));
    float num1 = fmaf(cfA1.x, xcA1, cfA1.y);
    float den1 = fmaf(cfA1.z, xcA1, cfA1.w);
    float o1 = (xA1 == xcA1) ? __fdividef(num1, den1) : xA1;
    float l1 = -1.3862943611198906f * __log2f(fabsf(den1));
    Ob[15*128] = o0; Ob[15*128 + 64] = o1;
    float s0 = wave_sum63(l0);
    float s1 = wave_sum63(l1);
    if (d == 63) {
      float2 v; v.x = s0; v.y = s1;
      *(float2*)(Lp + 30) = v;
    }
  }
#undef COARSE
#undef FINE
}

extern "C" void kernel_launch(void* const* d_in, const int* in_sizes, int n_in,
                              void* d_out, int out_size, void* d_ws, size_t ws_size,
                              hipStream_t stream) {
  const float* x  = (const float*)d_in[0];
  const float* uw = (const float*)d_in[1];
  const float* uh = (const float*)d_in[2];
  const float* ud = (const float*)d_in[3];
  const float* ul = (const float*)d_in[4];
  float* out = (float*)d_out;
  float* F = (float*)d_ws;
  nf_pre<<<DIM, 64, 0, stream>>>(uw, uh, ud, ul, F);
  nf_main<<<512, 1024, 0, stream>>>(x, F, out, out + (size_t)BATCH*DIM);
}

// Round 8
// 52.103 us; speedup vs baseline: 1.0446x; 1.0446x over previous
//
#include <hip/hip_runtime.h>

// NormalizingFlow: 4 layers of monotonic linear-rational splines (pyro-style),
// B=262144 rows, D=64 dims, K=8 bins.
//
// Each spline sub-piece (bin x lambda-half) is a Mobius map f(x)=(Ax+B)/(Cx+D);
// Mobius maps compose, so the 4-layer chain per dim is piecewise-Mobius with
// <= 61 pieces. Fused precompute builds per-(d,piece) det-normalized (det=1)
// ABSOLUTE coefficient matrices; main kernel: 2-level LDS search + one LDS
// coeff gather + Mobius; lad = -2*ln|den| (det==1); DPP wave reduce.
// 3-stage software pipeline (coarse+knot-issue / fine+coeff-issue / math)
// with sched_barrier(0) fences: every LDS read gets ~1 full iteration of
// independent work before its consumer.

#define BATCH 262144
#define DIM   64
#define NLAY  4
#define NK    8

// float offsets in d_ws (units: floats from base)
#define OFF_KN0 0       // [8][64][4] fine knots bnd[8c+0..3] (slot0 unused)
#define OFF_KN1 2048    // [8][64][4] fine knots bnd[8c+4..7]
#define OFF_CRS 4096    // [7][64] coarse knots bnd[8],bnd[16],...,bnd[56]
#define OFF_CF0 4544    // [61][64][4] piece coeffs (A,B,C,D) det-normalized

// Fused precompute: one block per dim d (64 blocks x 64 threads).
// Phase 1 parallelized over 32 threads: t = l*8 + k (layer l, bin k); each
// thread replicates the serial softmax-prefix rounding for its own bin.
__global__ void nf_pre(const float* __restrict__ uw, const float* __restrict__ uh,
                       const float* __restrict__ ud, const float* __restrict__ ul,
                       float* __restrict__ F) {
  __shared__ double Lb[NLAY][17], Ly[NLAY][17], LM[NLAY][16][4], Ld[NLAY][16];
  __shared__ double sx[64], Fb[65];
  int d = blockIdx.x;
  int t = threadIdx.x;

  if (t < 32) {
    int l = t >> 3, k = t & 7;
    const float* pw  = uw + (l*DIM + d)*NK;
    const float* ph  = uh + (l*DIM + d)*NK;
    const float* pdv = ud + (l*DIM + d)*(NK-1);
    const float* pl  = ul + (l*DIM + d)*NK;

    // widths softmax (serial-order rounding preserved)
    float ev[NK];
    float mw = pw[0];
    for (int j = 1; j < NK; ++j) mw = fmaxf(mw, pw[j]);
    float sw = 0.f;
    for (int j = 0; j < NK; ++j) { ev[j] = expf(pw[j] - mw); sw += ev[j]; }
    float invw = 1.f / sw;
    float cwe = 0.f, cwi = 0.f;
    for (int j = 0; j <= k; ++j) {
      float vj = 1e-3f + (1.f - 1e-3f * (float)NK) * (ev[j] * invw);
      cwe = cwi; cwi += vj;
    }
    float kwL = (k == 0) ? -3.f : 6.f * cwe - 3.f;
    float kwR = (k == 7) ?  3.f : 6.f * cwi - 3.f;
    float wwk = kwR - kwL;

    // heights softmax
    float mh = ph[0];
    for (int j = 1; j < NK; ++j) mh = fmaxf(mh, ph[j]);
    float sh = 0.f;
    for (int j = 0; j < NK; ++j) { ev[j] = expf(ph[j] - mh); sh += ev[j]; }
    float invh = 1.f / sh;
    float che = 0.f, chi = 0.f;
    for (int j = 0; j <= k; ++j) {
      float vj = 1e-3f + (1.f - 1e-3f * (float)NK) * (ev[j] * invh);
      che = chi; chi += vj;
    }
    float khL = (k == 0) ? -3.f : 6.f * che - 3.f;
    float khR = (k == 7) ?  3.f : 6.f * chi - 3.f;
    float hhk = khR - khL;

    // derivatives at both ends of bin k; lambda
    float dvk, dvk1;
    if (k == 0) dvk = 1.f;
    else { float u = pdv[k-1]; dvk  = 1e-3f + (fmaxf(u,0.f) + log1pf(expf(-fabsf(u)))); }
    if (k == 7) dvk1 = 1.f;
    else { float u = pdv[k];   dvk1 = 1e-3f + (fmaxf(u,0.f) + log1pf(expf(-fabsf(u)))); }
    float sg = 1.f / (1.f + expf(-pl[k]));
    float lmk = 0.95f * sg + 0.025f;

    float delta = hhk / wwk;
    float wbf = sqrtf(dvk / dvk1);
    float wcf = (lmk*dvk + (1.f-lmk)*wbf*dvk1) / delta;
    float yaf = khL, ybf = hhk + khL;
    float ycf = ((1.f-lmk)*yaf + lmk*wbf*ybf) / ((1.f-lmk) + lmk*wbf);

    if (k == 0) {
      Lb[l][0] = -3.0; Lb[l][16] = 3.0;
      Ly[l][0] = -3.0; Ly[l][16] = 3.0;
    }
    if (k) Lb[l][2*k] = (double)(kwL + 1.0e-6f);   // bin boundary (fp32 +EPS)
    Lb[l][2*k+1] = (double)kwL + (double)lmk*(double)wwk;  // theta==lambda
    Ly[l][2*k]   = (double)yaf;
    Ly[l][2*k+1] = (double)ycf;

    double icw = (double)kwL, iw = (double)wwk, il = (double)lmk;
    double wb = wbf, wc = wcf, ya = yaf, yb = ybf, yc = ycf;
    double n0 = ya*il, n1 = wc*yc - ya, d0 = il, d1 = wc - 1.0;
    double A = n1, Bv = n0*iw - n1*icw, C = d1, Dv = d0*iw - d1*icw;
    LM[l][2*k][0]=A; LM[l][2*k][1]=Bv; LM[l][2*k][2]=C; LM[l][2*k][3]=Dv;
    Ld[l][2*k] = log2(A*Dv - Bv*C);
    n0 = wc*yc - il*wb*yb; n1 = wb*yb - wc*yc; d0 = wc - il*wb; d1 = wb - wc;
    A = n1; Bv = n0*iw - n1*icw; C = d1; Dv = d0*iw - d1*icw;
    LM[l][2*k+1][0]=A; LM[l][2*k+1][1]=Bv; LM[l][2*k+1][2]=C; LM[l][2*k+1][3]=Dv;
    Ld[l][2*k+1] = log2(A*Dv - Bv*C);
  }
  __syncthreads();

  if (t < 60) {
    int lp  = t / 15;
    int mth = t % 15 + 1;
    double x = Lb[lp][mth];
    for (int q = lp - 1; q >= 0; --q) {
      int j = 0;
      for (int k = 1; k <= 15; ++k) j += (x >= Ly[q][k]) ? 1 : 0;
      const double* M = LM[q][j];
      x = (M[3]*x - M[1]) / (M[0] - M[2]*x);  // Mobius inverse
    }
    sx[t] = x;
  }
  __syncthreads();
  if (t < 60) {
    double x = sx[t];
    int r = 0;
    for (int s2 = 0; s2 < 60; ++s2) {
      double o = sx[s2];
      r += (o < x || (o == x && s2 < t)) ? 1 : 0;
    }
    Fb[r+1] = x;
  }
  if (t == 0)  Fb[0] = -3.0;
  if (t >= 60) Fb[t+1] = 3.0;   // Fb[61..64] geometry pads
  __syncthreads();

  // fp32 search tables
  {
    int j = t;
    float bf;
    if (j == 0)       bf = -3.0f;
    else if (j <= 60) bf = (float)Fb[j];
    else              bf = 1e30f;         // pads: never counted
    int cw = j >> 3, r8 = j & 7;
    if (r8 < 4) F[OFF_KN0 + (cw*DIM + d)*4 + r8]     = bf;
    else        F[OFF_KN1 + (cw*DIM + d)*4 + (r8-4)] = bf;
    if (j >= 8 && (j & 7) == 0 && j <= 56) F[OFF_CRS + (j/8 - 1)*DIM + d] = bf;
  }

  // per-piece composed ABSOLUTE coefficients (no recentering), det -> 1
  if (t < 61) {
    int p = t;
    double bl = Fb[p], br = Fb[p+1];
    float xmf = (float)(0.5*(bl+br));
    xmf = fminf(fmaxf(xmf, -3.f), 3.f);
    double y = (double)xmf;
    double A=1.0, Bv=0.0, C=0.0, Dv=1.0, ld2 = 0.0;
    for (int q = 0; q < NLAY; ++q) {
      int j = 0;
      for (int k = 1; k <= 15; ++k) j += (y >= Lb[q][k]) ? 1 : 0;
      const double* M = LM[q][j];
      ld2 += Ld[q][j];
      double A2 = M[0]*A + M[1]*C, B2 = M[0]*Bv + M[1]*Dv;
      double C2 = M[2]*A + M[3]*C, D2 = M[2]*Bv + M[3]*Dv;
      y = (M[0]*y + M[1]) / (M[2]*y + M[3]);
      A=A2; Bv=B2; C=C2; Dv=D2;
    }
    double sinv = exp2(-0.5 * ld2);              // det -> 1
    float4 c4;
    c4.x = (float)(A*sinv); c4.y = (float)(Bv*sinv);
    c4.z = (float)(C*sinv); c4.w = (float)(Dv*sinv);
    *(float4*)(F + OFF_CF0 + (size_t)(p*DIM + d)*4) = c4;
  }
}

template <int CTRL>
__device__ __forceinline__ float dpp_add(float x) {
  int yi = __builtin_amdgcn_update_dpp(0, __float_as_int(x), CTRL, 0xF, 0xF, false);
  return x + __int_as_float(yi);
}
// wave64 sum -> lane 63 (rocPRIM gfx9 sequence)
__device__ __forceinline__ float wave_sum63(float x) {
  x = dpp_add<0x111>(x);  // row_shr:1
  x = dpp_add<0x112>(x);  // row_shr:2
  x = dpp_add<0x114>(x);  // row_shr:4
  x = dpp_add<0x118>(x);  // row_shr:8
  x = dpp_add<0x142>(x);  // row_bcast:15
  x = dpp_add<0x143>(x);  // row_bcast:31
  return x;
}

// Main: lane = dim; wave owns 32 rows as 16 units of 2, 3-stage pipeline:
//   iter it:  R1: coarse(unit it+2) + issue its 4 knot ds_reads + X prefetch
//             R2: math(unit it)   [coeffs issued at iter it-1 -> ~full iter gap]
//             R3: fine(unit it+1) + issue its 2 coeff ds_reads
// sched_barrier(0) pins region order; pipeline state is explicitly live.
__global__ __launch_bounds__(1024, 4) void nf_main(const float* __restrict__ X,
                                                   const float* __restrict__ F,
                                                   float* __restrict__ OUT,
                                                   float* __restrict__ LDo) {
  __shared__ float smem[19712];   // [0,4096): knots  [4096,19712): 61 coeff rows
  int t = threadIdx.x;
  {
    float4* dst = (float4*)smem;
    const float4* kt = (const float4*)(F + OFF_KN0);
    dst[t] = kt[t];
    const float4* ct = (const float4*)(F + OFF_CF0);
    for (int i = t; i < 3904; i += 1024) dst[1024 + i] = ct[i];
  }
  int d = t & 63;
  float k1 = F[OFF_CRS + 0*DIM + d];
  float k2 = F[OFF_CRS + 1*DIM + d];
  float k3 = F[OFF_CRS + 2*DIM + d];
  float k4 = F[OFF_CRS + 3*DIM + d];
  float k5 = F[OFF_CRS + 4*DIM + d];
  float k6 = F[OFF_CRS + 5*DIM + d];
  float k7 = F[OFF_CRS + 6*DIM + d];
  __syncthreads();
  const float4* skv = (const float4*)smem;

  int gw = blockIdx.x * 16 + (t >> 6);          // 0..8191; wave owns 32 rows
  const float* Xb = X   + (size_t)gw*32*DIM + d;
  float*       Ob = OUT + (size_t)gw*32*DIM + d;
  float*       Lp = LDo + (size_t)gw*32;

#define COARSE(xc) ((xc>=k1)+(xc>=k2)+(xc>=k3)+(xc>=k4)+(xc>=k5)+(xc>=k6)+(xc>=k7))
#define FINE(xc, cc, f0, f1) \
  ((cc<<3) + (int)(xc>=f0.y)+(int)(xc>=f0.z)+(int)(xc>=f0.w)+(int)(xc>=f1.x) \
           + (int)(xc>=f1.y)+(int)(xc>=f1.z)+(int)(xc>=f1.w))

  // ---- prologue ----
  // slot A = unit 0 (full chain), slot B = unit 1 (through knots), slot C = unit 2 (x only)
  float xA0 = Xb[0],   xA1 = Xb[64];
  float xB0 = Xb[128], xB1 = Xb[192];
  float xC0 = Xb[256], xC1 = Xb[320];
  float xcA0 = fminf(fmaxf(xA0, -3.f), 3.f);
  float xcA1 = fminf(fmaxf(xA1, -3.f), 3.f);
  float4 cfA0, cfA1;
  {
    int c0 = COARSE(xcA0), c1 = COARSE(xcA1);
    float4 f00 = skv[(c0<<6)+d], f01 = skv[512+(c0<<6)+d];
    float4 f10 = skv[(c1<<6)+d], f11 = skv[512+(c1<<6)+d];
    int p0 = FINE(xcA0, c0, f00, f01);
    int p1 = FINE(xcA1, c1, f10, f11);
    cfA0 = skv[1024+(p0<<6)+d];
    cfA1 = skv[1024+(p1<<6)+d];
  }
  float xcB0 = fminf(fmaxf(xB0, -3.f), 3.f);
  float xcB1 = fminf(fmaxf(xB1, -3.f), 3.f);
  int cB0 = COARSE(xcB0), cB1 = COARSE(xcB1);
  float4 fB00 = skv[(cB0<<6)+d], fB01 = skv[512+(cB0<<6)+d];
  float4 fB10 = skv[(cB1<<6)+d], fB11 = skv[512+(cB1<<6)+d];

  for (int it = 0; it < 16; ++it) {
    // ---- R1: coarse(slot C = unit it+2) + issue knot reads; X prefetch ----
    float xcC0 = fminf(fmaxf(xC0, -3.f), 3.f);
    float xcC1 = fminf(fmaxf(xC1, -3.f), 3.f);
    int cC0 = COARSE(xcC0), cC1 = COARSE(xcC1);
    float4 fC00 = skv[(cC0<<6)+d], fC01 = skv[512+(cC0<<6)+d];
    float4 fC10 = skv[(cC1<<6)+d], fC11 = skv[512+(cC1<<6)+d];
    int u3 = (it + 3 < 16) ? (it + 3) : 15;
    float xN0 = Xb[u3*128], xN1 = Xb[u3*128 + 64];
    __builtin_amdgcn_sched_barrier(0);
    // ---- R2: math(slot A = unit it), coeffs issued last iteration ----
    float num0 = fmaf(cfA0.x, xcA0, cfA0.y);
    float den0 = fmaf(cfA0.z, xcA0, cfA0.w);
    float o0 = (xA0 == xcA0) ? __fdividef(num0, den0) : xA0;
    float l0 = -1.3862943611198906f * __log2f(fabsf(den0));
    float num1 = fmaf(cfA1.x, xcA1, cfA1.y);
    float den1 = fmaf(cfA1.z, xcA1, cfA1.w);
    float o1 = (xA1 == xcA1) ? __fdividef(num1, den1) : xA1;
    float l1 = -1.3862943611198906f * __log2f(fabsf(den1));
    Ob[it*128] = o0; Ob[it*128 + 64] = o1;
    float s0 = wave_sum63(l0);
    float s1 = wave_sum63(l1);
    if (d == 63) {
      float2 v; v.x = s0; v.y = s1;
      *(float2*)(Lp + 2*it) = v;
    }
    __builtin_amdgcn_sched_barrier(0);
    // ---- R3: fine(slot B = unit it+1) + issue coeff reads ----
    int p0 = FINE(xcB0, cB0, fB00, fB01);
    int p1 = FINE(xcB1, cB1, fB10, fB11);
    float4 cfN0 = skv[1024+(p0<<6)+d];
    float4 cfN1 = skv[1024+(p1<<6)+d];
    // ---- shift pipeline ----
    xA0 = xB0; xA1 = xB1; xcA0 = xcB0; xcA1 = xcB1; cfA0 = cfN0; cfA1 = cfN1;
    xB0 = xC0; xB1 = xC1; xcB0 = xcC0; xcB1 = xcC1; cB0 = cC0; cB1 = cC1;
    fB00 = fC00; fB01 = fC01; fB10 = fC10; fB11 = fC11;
    xC0 = xN0; xC1 = xN1;
  }
#undef COARSE
#undef FINE
}

extern "C" void kernel_launch(void* const* d_in, const int* in_sizes, int n_in,
                              void* d_out, int out_size, void* d_ws, size_t ws_size,
                              hipStream_t stream) {
  const float* x  = (const float*)d_in[0];
  const float* uw = (const float*)d_in[1];
  const float* uh = (const float*)d_in[2];
  const float* ud = (const float*)d_in[3];
  const float* ul = (const float*)d_in[4];
  float* out = (float*)d_out;
  float* F = (float*)d_ws;
  nf_pre<<<DIM, 64, 0, stream>>>(uw, uh, ud, ul, F);
  nf_main<<<512, 1024, 0, stream>>>(x, F, out, out + (size_t)BATCH*DIM);
}

// Round 9
// 45.734 us; speedup vs baseline: 1.1900x; 1.1393x over previous
//
#include <hip/hip_runtime.h>

// NormalizingFlow: 4 layers of monotonic linear-rational splines (pyro-style),
// B=262144 rows, D=64 dims, K=8 bins.
//
// Each spline sub-piece (bin x lambda-half) is a Mobius map f(x)=(Ax+B)/(Cx+D);
// Mobius maps compose, so the 4-layer chain per dim is piecewise-Mobius with
// <= 61 pieces. Fused precompute (parallel phase 1) builds per-(d,piece)
// det-normalized (det=1) ABSOLUTE coefficient matrices; main kernel: 2-level
// LDS search + one LDS coeff gather + Mobius; lad = -2*ln|den| (det==1);
// DPP wave reduce. 2-slot software pipeline + sched_barrier fences (best-known
// R6 config, 40.6us), partially unrolled x5 to kill the pipeline-shift movs.

#define BATCH 262144
#define DIM   64
#define NLAY  4
#define NK    8

// float offsets in d_ws (units: floats from base)
#define OFF_KN0 0       // [8][64][4] fine knots bnd[8c+0..3] (slot0 unused)
#define OFF_KN1 2048    // [8][64][4] fine knots bnd[8c+4..7]
#define OFF_CRS 4096    // [7][64] coarse knots bnd[8],bnd[16],...,bnd[56]
#define OFF_CF0 4544    // [61][64][4] piece coeffs (A,B,C,D) det-normalized

// Fused precompute: one block per dim d (64 blocks x 64 threads).
// Phase 1 parallelized over 32 threads: t = l*8 + k (layer l, bin k); each
// thread replicates the serial softmax-prefix rounding for its own bin.
__global__ void nf_pre(const float* __restrict__ uw, const float* __restrict__ uh,
                       const float* __restrict__ ud, const float* __restrict__ ul,
                       float* __restrict__ F) {
  __shared__ double Lb[NLAY][17], Ly[NLAY][17], LM[NLAY][16][4], Ld[NLAY][16];
  __shared__ double sx[64], Fb[65];
  int d = blockIdx.x;
  int t = threadIdx.x;

  if (t < 32) {
    int l = t >> 3, k = t & 7;
    const float* pw  = uw + (l*DIM + d)*NK;
    const float* ph  = uh + (l*DIM + d)*NK;
    const float* pdv = ud + (l*DIM + d)*(NK-1);
    const float* pl  = ul + (l*DIM + d)*NK;

    // widths softmax (serial-order rounding preserved)
    float ev[NK];
    float mw = pw[0];
    for (int j = 1; j < NK; ++j) mw = fmaxf(mw, pw[j]);
    float sw = 0.f;
    for (int j = 0; j < NK; ++j) { ev[j] = expf(pw[j] - mw); sw += ev[j]; }
    float invw = 1.f / sw;
    float cwe = 0.f, cwi = 0.f;
    for (int j = 0; j <= k; ++j) {
      float vj = 1e-3f + (1.f - 1e-3f * (float)NK) * (ev[j] * invw);
      cwe = cwi; cwi += vj;
    }
    float kwL = (k == 0) ? -3.f : 6.f * cwe - 3.f;
    float kwR = (k == 7) ?  3.f : 6.f * cwi - 3.f;
    float wwk = kwR - kwL;

    // heights softmax
    float mh = ph[0];
    for (int j = 1; j < NK; ++j) mh = fmaxf(mh, ph[j]);
    float sh = 0.f;
    for (int j = 0; j < NK; ++j) { ev[j] = expf(ph[j] - mh); sh += ev[j]; }
    float invh = 1.f / sh;
    float che = 0.f, chi = 0.f;
    for (int j = 0; j <= k; ++j) {
      float vj = 1e-3f + (1.f - 1e-3f * (float)NK) * (ev[j] * invh);
      che = chi; chi += vj;
    }
    float khL = (k == 0) ? -3.f : 6.f * che - 3.f;
    float khR = (k == 7) ?  3.f : 6.f * chi - 3.f;
    float hhk = khR - khL;

    // derivatives at both ends of bin k; lambda
    float dvk, dvk1;
    if (k == 0) dvk = 1.f;
    else { float u = pdv[k-1]; dvk  = 1e-3f + (fmaxf(u,0.f) + log1pf(expf(-fabsf(u)))); }
    if (k == 7) dvk1 = 1.f;
    else { float u = pdv[k];   dvk1 = 1e-3f + (fmaxf(u,0.f) + log1pf(expf(-fabsf(u)))); }
    float sg = 1.f / (1.f + expf(-pl[k]));
    float lmk = 0.95f * sg + 0.025f;

    float delta = hhk / wwk;
    float wbf = sqrtf(dvk / dvk1);
    float wcf = (lmk*dvk + (1.f-lmk)*wbf*dvk1) / delta;
    float yaf = khL, ybf = hhk + khL;
    float ycf = ((1.f-lmk)*yaf + lmk*wbf*ybf) / ((1.f-lmk) + lmk*wbf);

    if (k == 0) {
      Lb[l][0] = -3.0; Lb[l][16] = 3.0;
      Ly[l][0] = -3.0; Ly[l][16] = 3.0;
    }
    if (k) Lb[l][2*k] = (double)(kwL + 1.0e-6f);   // bin boundary (fp32 +EPS)
    Lb[l][2*k+1] = (double)kwL + (double)lmk*(double)wwk;  // theta==lambda
    Ly[l][2*k]   = (double)yaf;
    Ly[l][2*k+1] = (double)ycf;

    double icw = (double)kwL, iw = (double)wwk, il = (double)lmk;
    double wb = wbf, wc = wcf, ya = yaf, yb = ybf, yc = ycf;
    double n0 = ya*il, n1 = wc*yc - ya, d0 = il, d1 = wc - 1.0;
    double A = n1, Bv = n0*iw - n1*icw, C = d1, Dv = d0*iw - d1*icw;
    LM[l][2*k][0]=A; LM[l][2*k][1]=Bv; LM[l][2*k][2]=C; LM[l][2*k][3]=Dv;
    Ld[l][2*k] = log2(A*Dv - Bv*C);
    n0 = wc*yc - il*wb*yb; n1 = wb*yb - wc*yc; d0 = wc - il*wb; d1 = wb - wc;
    A = n1; Bv = n0*iw - n1*icw; C = d1; Dv = d0*iw - d1*icw;
    LM[l][2*k+1][0]=A; LM[l][2*k+1][1]=Bv; LM[l][2*k+1][2]=C; LM[l][2*k+1][3]=Dv;
    Ld[l][2*k+1] = log2(A*Dv - Bv*C);
  }
  __syncthreads();

  if (t < 60) {
    int lp  = t / 15;
    int mth = t % 15 + 1;
    double x = Lb[lp][mth];
    for (int q = lp - 1; q >= 0; --q) {
      int j = 0;
      for (int k = 1; k <= 15; ++k) j += (x >= Ly[q][k]) ? 1 : 0;
      const double* M = LM[q][j];
      x = (M[3]*x - M[1]) / (M[0] - M[2]*x);  // Mobius inverse
    }
    sx[t] = x;
  }
  __syncthreads();
  if (t < 60) {
    double x = sx[t];
    int r = 0;
    for (int s2 = 0; s2 < 60; ++s2) {
      double o = sx[s2];
      r += (o < x || (o == x && s2 < t)) ? 1 : 0;
    }
    Fb[r+1] = x;
  }
  if (t == 0)  Fb[0] = -3.0;
  if (t >= 60) Fb[t+1] = 3.0;   // Fb[61..64] geometry pads
  __syncthreads();

  // fp32 search tables
  {
    int j = t;
    float bf;
    if (j == 0)       bf = -3.0f;
    else if (j <= 60) bf = (float)Fb[j];
    else              bf = 1e30f;         // pads: never counted
    int cw = j >> 3, r8 = j & 7;
    if (r8 < 4) F[OFF_KN0 + (cw*DIM + d)*4 + r8]     = bf;
    else        F[OFF_KN1 + (cw*DIM + d)*4 + (r8-4)] = bf;
    if (j >= 8 && (j & 7) == 0 && j <= 56) F[OFF_CRS + (j/8 - 1)*DIM + d] = bf;
  }

  // per-piece composed ABSOLUTE coefficients (no recentering), det -> 1
  if (t < 61) {
    int p = t;
    double bl = Fb[p], br = Fb[p+1];
    float xmf = (float)(0.5*(bl+br));
    xmf = fminf(fmaxf(xmf, -3.f), 3.f);
    double y = (double)xmf;
    double A=1.0, Bv=0.0, C=0.0, Dv=1.0, ld2 = 0.0;
    for (int q = 0; q < NLAY; ++q) {
      int j = 0;
      for (int k = 1; k <= 15; ++k) j += (y >= Lb[q][k]) ? 1 : 0;
      const double* M = LM[q][j];
      ld2 += Ld[q][j];
      double A2 = M[0]*A + M[1]*C, B2 = M[0]*Bv + M[1]*Dv;
      double C2 = M[2]*A + M[3]*C, D2 = M[2]*Bv + M[3]*Dv;
      y = (M[0]*y + M[1]) / (M[2]*y + M[3]);
      A=A2; Bv=B2; C=C2; Dv=D2;
    }
    double sinv = exp2(-0.5 * ld2);              // det -> 1
    float4 c4;
    c4.x = (float)(A*sinv); c4.y = (float)(Bv*sinv);
    c4.z = (float)(C*sinv); c4.w = (float)(Dv*sinv);
    *(float4*)(F + OFF_CF0 + (size_t)(p*DIM + d)*4) = c4;
  }
}

template <int CTRL>
__device__ __forceinline__ float dpp_add(float x) {
  int yi = __builtin_amdgcn_update_dpp(0, __float_as_int(x), CTRL, 0xF, 0xF, false);
  return x + __int_as_float(yi);
}
// wave64 sum -> lane 63 (rocPRIM gfx9 sequence)
__device__ __forceinline__ float wave_sum63(float x) {
  x = dpp_add<0x111>(x);  // row_shr:1
  x = dpp_add<0x112>(x);  // row_shr:2
  x = dpp_add<0x114>(x);  // row_shr:4
  x = dpp_add<0x118>(x);  // row_shr:8
  x = dpp_add<0x142>(x);  // row_bcast:15
  x = dpp_add<0x143>(x);  // row_bcast:31
  return x;
}

// Main: lane = dim; wave owns 32 rows as 16 units of 2, software-pipelined:
//   R1: coarse(unit k+1) + issue fine-knot reads + X prefetch(unit k+2)
//   R2: math(unit k) with coeffs read LAST iteration (latency hidden)
//   R3: fine-search(unit k+1) + issue coeff reads
// sched_barrier(0) pins region order. #pragma unroll 5 renames the rotating
// pipeline registers (kills ~12 v_mov/iter) and folds store offsets.
__global__ __launch_bounds__(1024, 4) void nf_main(const float* __restrict__ X,
                                                   const float* __restrict__ F,
                                                   float* __restrict__ OUT,
                                                   float* __restrict__ LDo) {
  __shared__ float smem[19712];   // [0,4096): knots  [4096,19712): 61 coeff rows
  int t = threadIdx.x;
  {
    float4* dst = (float4*)smem;
    const float4* kt = (const float4*)(F + OFF_KN0);
    dst[t] = kt[t];
    const float4* ct = (const float4*)(F + OFF_CF0);
    for (int i = t; i < 3904; i += 1024) dst[1024 + i] = ct[i];
  }
  int d = t & 63;
  float k1 = F[OFF_CRS + 0*DIM + d];
  float k2 = F[OFF_CRS + 1*DIM + d];
  float k3 = F[OFF_CRS + 2*DIM + d];
  float k4 = F[OFF_CRS + 3*DIM + d];
  float k5 = F[OFF_CRS + 4*DIM + d];
  float k6 = F[OFF_CRS + 5*DIM + d];
  float k7 = F[OFF_CRS + 6*DIM + d];
  __syncthreads();
  const float4* skv = (const float4*)smem;

  int gw = blockIdx.x * 16 + (t >> 6);          // 0..8191; wave owns 32 rows
  const float* Xb = X   + (size_t)gw*32*DIM + d;
  float*       Ob = OUT + (size_t)gw*32*DIM + d;
  float*       Lp = LDo + (size_t)gw*32;

#define COARSE(xc) ((xc>=k1)+(xc>=k2)+(xc>=k3)+(xc>=k4)+(xc>=k5)+(xc>=k6)+(xc>=k7))
#define FINE(xc, cc, f0, f1) \
  ((cc<<3) + (int)(xc>=f0.y)+(int)(xc>=f0.z)+(int)(xc>=f0.w)+(int)(xc>=f1.x) \
           + (int)(xc>=f1.y)+(int)(xc>=f1.z)+(int)(xc>=f1.w))

  // ---- prologue: full search of unit 0; load x of unit 1 ----
  float xA0 = Xb[0], xA1 = Xb[64];
  float xB0 = Xb[128], xB1 = Xb[192];
  float xcA0 = fminf(fmaxf(xA0, -3.f), 3.f);
  float xcA1 = fminf(fmaxf(xA1, -3.f), 3.f);
  float4 cfA0, cfA1;
  {
    int c0 = COARSE(xcA0), c1 = COARSE(xcA1);
    float4 f00 = skv[(c0<<6)+d], f01 = skv[512+(c0<<6)+d];
    float4 f10 = skv[(c1<<6)+d], f11 = skv[512+(c1<<6)+d];
    int p0 = FINE(xcA0, c0, f00, f01);
    int p1 = FINE(xcA1, c1, f10, f11);
    cfA0 = skv[1024+(p0<<6)+d];
    cfA1 = skv[1024+(p1<<6)+d];
  }

#pragma unroll 5
  for (int it = 0; it < 15; ++it) {
    // ---- R1: coarse(unit it+1), issue fine reads; prefetch x(unit it+2) ----
    float xcB0 = fminf(fmaxf(xB0, -3.f), 3.f);
    float xcB1 = fminf(fmaxf(xB1, -3.f), 3.f);
    int cB0 = COARSE(xcB0), cB1 = COARSE(xcB1);
    float4 f00 = skv[(cB0<<6)+d], f01 = skv[512+(cB0<<6)+d];
    float4 f10 = skv[(cB1<<6)+d], f11 = skv[512+(cB1<<6)+d];
    int u2 = (it < 14) ? (it + 2) : 15;
    float xF0 = Xb[u2*128], xF1 = Xb[u2*128 + 64];
    __builtin_amdgcn_sched_barrier(0);
    // ---- R2: math(unit it) using cfA (read last iteration) ----
    float num0 = fmaf(cfA0.x, xcA0, cfA0.y);
    float den0 = fmaf(cfA0.z, xcA0, cfA0.w);
    float o0 = (xA0 == xcA0) ? __fdividef(num0, den0) : xA0;
    float l0 = -1.3862943611198906f * __log2f(fabsf(den0));
    float num1 = fmaf(cfA1.x, xcA1, cfA1.y);
    float den1 = fmaf(cfA1.z, xcA1, cfA1.w);
    float o1 = (xA1 == xcA1) ? __fdividef(num1, den1) : xA1;
    float l1 = -1.3862943611198906f * __log2f(fabsf(den1));
    Ob[it*128] = o0; Ob[it*128 + 64] = o1;
    float s0 = wave_sum63(l0);
    float s1 = wave_sum63(l1);
    if (d == 63) {
      float2 v; v.x = s0; v.y = s1;
      *(float2*)(Lp + 2*it) = v;
    }
    __builtin_amdgcn_sched_barrier(0);
    // ---- R3: fine-search(unit it+1) + issue coeff reads ----
    int p0 = FINE(xcB0, cB0, f00, f01);
    int p1 = FINE(xcB1, cB1, f10, f11);
    cfA0 = skv[1024+(p0<<6)+d];
    cfA1 = skv[1024+(p1<<6)+d];
    xA0 = xB0; xA1 = xB1; xcA0 = xcB0; xcA1 = xcB1;
    xB0 = xF0; xB1 = xF1;
  }
  // ---- epilogue: math(unit 15) ----
  {
    float num0 = fmaf(cfA0.x, xcA0, cfA0.y);
    float den0 = fmaf(cfA0.z, xcA0, cfA0.w);
    float o0 = (xA0 == xcA0) ? __fdividef(num0, den0) : xA0;
    float l0 = -1.3862943611198906f * __log2f(fabsf(den0));
    float num1 = fmaf(cfA1.x, xcA1, cfA1.y);
    float den1 = fmaf(cfA1.z, xcA1, cfA1.w);
    float o1 = (xA1 == xcA1) ? __fdividef(num1, den1) : xA1;
    float l1 = -1.3862943611198906f * __log2f(fabsf(den1));
    Ob[15*128] = o0; Ob[15*128 + 64] = o1;
    float s0 = wave_sum63(l0);
    float s1 = wave_sum63(l1);
    if (d == 63) {
      float2 v; v.x = s0; v.y = s1;
      *(float2*)(Lp + 30) = v;
    }
  }
#undef COARSE
#undef FINE
}

extern "C" void kernel_launch(void* const* d_in, const int* in_sizes, int n_in,
                              void* d_out, int out_size, void* d_ws, size_t ws_size,
                              hipStream_t stream) {
  const float* x  = (const float*)d_in[0];
  const float* uw = (const float*)d_in[1];
  const float* uh = (const float*)d_in[2];
  const float* ud = (const float*)d_in[3];
  const float* ul = (const float*)d_in[4];
  float* out = (float*)d_out;
  float* F = (float*)d_ws;
  nf_pre<<<DIM, 64, 0, stream>>>(uw, uh, ud, ul, F);
  nf_main<<<512, 1024, 0, stream>>>(x, F, out, out + (size_t)BATCH*DIM);
}

// Round 10
// 43.879 us; speedup vs baseline: 1.2404x; 1.0423x over previous
//
#include <hip/hip_runtime.h>

// NormalizingFlow: 4 layers of monotonic linear-rational splines (pyro-style),
// B=262144 rows, D=64 dims, K=8 bins.
//
// Each spline sub-piece (bin x lambda-half) is a Mobius map f(x)=(Ax+B)/(Cx+D);
// Mobius maps compose, so the 4-layer chain per dim is piecewise-Mobius with
// <= 61 pieces. Fused precompute (parallel phase 1) builds per-(d,piece)
// det-normalized (det=1) ABSOLUTE coefficient matrices; main kernel: 2-level
// LDS search + one LDS coeff gather + Mobius; lad = -2*ln|den| (det==1);
// single-instruction DPP wave reduce (bound_ctrl=1 folds to v_add_f32_dpp).
// 2-slot software pipeline + sched_barrier fences; 3 groups x 5 units with
// group-local pointers so all global offsets fold into the instruction.

#define BATCH 262144
#define DIM   64
#define NLAY  4
#define NK    8

// float offsets in d_ws (units: floats from base)
#define OFF_KN0 0       // [8][64][4] fine knots bnd[8c+0..3] (slot0 unused)
#define OFF_KN1 2048    // [8][64][4] fine knots bnd[8c+4..7]
#define OFF_CRS 4096    // [7][64] coarse knots bnd[8],bnd[16],...,bnd[56]
#define OFF_CF0 4544    // [61][64][4] piece coeffs (A,B,C,D) det-normalized

// Fused precompute: one block per dim d (64 blocks x 64 threads).
// Phase 1 parallelized over 32 threads: t = l*8 + k (layer l, bin k); each
// thread replicates the serial softmax-prefix rounding for its own bin.
__global__ void nf_pre(const float* __restrict__ uw, const float* __restrict__ uh,
                       const float* __restrict__ ud, const float* __restrict__ ul,
                       float* __restrict__ F) {
  __shared__ double Lb[NLAY][17], Ly[NLAY][17], LM[NLAY][16][4], Ld[NLAY][16];
  __shared__ double sx[64], Fb[65];
  int d = blockIdx.x;
  int t = threadIdx.x;

  if (t < 32) {
    int l = t >> 3, k = t & 7;
    const float* pw  = uw + (l*DIM + d)*NK;
    const float* ph  = uh + (l*DIM + d)*NK;
    const float* pdv = ud + (l*DIM + d)*(NK-1);
    const float* pl  = ul + (l*DIM + d)*NK;

    // widths softmax (serial-order rounding preserved)
    float ev[NK];
    float mw = pw[0];
    for (int j = 1; j < NK; ++j) mw = fmaxf(mw, pw[j]);
    float sw = 0.f;
    for (int j = 0; j < NK; ++j) { ev[j] = expf(pw[j] - mw); sw += ev[j]; }
    float invw = 1.f / sw;
    float cwe = 0.f, cwi = 0.f;
    for (int j = 0; j <= k; ++j) {
      float vj = 1e-3f + (1.f - 1e-3f * (float)NK) * (ev[j] * invw);
      cwe = cwi; cwi += vj;
    }
    float kwL = (k == 0) ? -3.f : 6.f * cwe - 3.f;
    float kwR = (k == 7) ?  3.f : 6.f * cwi - 3.f;
    float wwk = kwR - kwL;

    // heights softmax
    float mh = ph[0];
    for (int j = 1; j < NK; ++j) mh = fmaxf(mh, ph[j]);
    float sh = 0.f;
    for (int j = 0; j < NK; ++j) { ev[j] = expf(ph[j] - mh); sh += ev[j]; }
    float invh = 1.f / sh;
    float che = 0.f, chi = 0.f;
    for (int j = 0; j <= k; ++j) {
      float vj = 1e-3f + (1.f - 1e-3f * (float)NK) * (ev[j] * invh);
      che = chi; chi += vj;
    }
    float khL = (k == 0) ? -3.f : 6.f * che - 3.f;
    float khR = (k == 7) ?  3.f : 6.f * chi - 3.f;
    float hhk = khR - khL;

    // derivatives at both ends of bin k; lambda
    float dvk, dvk1;
    if (k == 0) dvk = 1.f;
    else { float u = pdv[k-1]; dvk  = 1e-3f + (fmaxf(u,0.f) + log1pf(expf(-fabsf(u)))); }
    if (k == 7) dvk1 = 1.f;
    else { float u = pdv[k];   dvk1 = 1e-3f + (fmaxf(u,0.f) + log1pf(expf(-fabsf(u)))); }
    float sg = 1.f / (1.f + expf(-pl[k]));
    float lmk = 0.95f * sg + 0.025f;

    float delta = hhk / wwk;
    float wbf = sqrtf(dvk / dvk1);
    float wcf = (lmk*dvk + (1.f-lmk)*wbf*dvk1) / delta;
    float yaf = khL, ybf = hhk + khL;
    float ycf = ((1.f-lmk)*yaf + lmk*wbf*ybf) / ((1.f-lmk) + lmk*wbf);

    if (k == 0) {
      Lb[l][0] = -3.0; Lb[l][16] = 3.0;
      Ly[l][0] = -3.0; Ly[l][16] = 3.0;
    }
    if (k) Lb[l][2*k] = (double)(kwL + 1.0e-6f);   // bin boundary (fp32 +EPS)
    Lb[l][2*k+1] = (double)kwL + (double)lmk*(double)wwk;  // theta==lambda
    Ly[l][2*k]   = (double)yaf;
    Ly[l][2*k+1] = (double)ycf;

    double icw = (double)kwL, iw = (double)wwk, il = (double)lmk;
    double wb = wbf, wc = wcf, ya = yaf, yb = ybf, yc = ycf;
    double n0 = ya*il, n1 = wc*yc - ya, d0 = il, d1 = wc - 1.0;
    double A = n1, Bv = n0*iw - n1*icw, C = d1, Dv = d0*iw - d1*icw;
    LM[l][2*k][0]=A; LM[l][2*k][1]=Bv; LM[l][2*k][2]=C; LM[l][2*k][3]=Dv;
    Ld[l][2*k] = log2(A*Dv - Bv*C);
    n0 = wc*yc - il*wb*yb; n1 = wb*yb - wc*yc; d0 = wc - il*wb; d1 = wb - wc;
    A = n1; Bv = n0*iw - n1*icw; C = d1; Dv = d0*iw - d1*icw;
    LM[l][2*k+1][0]=A; LM[l][2*k+1][1]=Bv; LM[l][2*k+1][2]=C; LM[l][2*k+1][3]=Dv;
    Ld[l][2*k+1] = log2(A*Dv - Bv*C);
  }
  __syncthreads();

  if (t < 60) {
    int lp  = t / 15;
    int mth = t % 15 + 1;
    double x = Lb[lp][mth];
    for (int q = lp - 1; q >= 0; --q) {
      int j = 0;
      for (int k = 1; k <= 15; ++k) j += (x >= Ly[q][k]) ? 1 : 0;
      const double* M = LM[q][j];
      x = (M[3]*x - M[1]) / (M[0] - M[2]*x);  // Mobius inverse
    }
    sx[t] = x;
  }
  __syncthreads();
  if (t < 60) {
    double x = sx[t];
    int r = 0;
    for (int s2 = 0; s2 < 60; ++s2) {
      double o = sx[s2];
      r += (o < x || (o == x && s2 < t)) ? 1 : 0;
    }
    Fb[r+1] = x;
  }
  if (t == 0)  Fb[0] = -3.0;
  if (t >= 60) Fb[t+1] = 3.0;   // Fb[61..64] geometry pads
  __syncthreads();

  // fp32 search tables
  {
    int j = t;
    float bf;
    if (j == 0)       bf = -3.0f;
    else if (j <= 60) bf = (float)Fb[j];
    else              bf = 1e30f;         // pads: never counted
    int cw = j >> 3, r8 = j & 7;
    if (r8 < 4) F[OFF_KN0 + (cw*DIM + d)*4 + r8]     = bf;
    else        F[OFF_KN1 + (cw*DIM + d)*4 + (r8-4)] = bf;
    if (j >= 8 && (j & 7) == 0 && j <= 56) F[OFF_CRS + (j/8 - 1)*DIM + d] = bf;
  }

  // per-piece composed ABSOLUTE coefficients (no recentering), det -> 1
  if (t < 61) {
    int p = t;
    double bl = Fb[p], br = Fb[p+1];
    float xmf = (float)(0.5*(bl+br));
    xmf = fminf(fmaxf(xmf, -3.f), 3.f);
    double y = (double)xmf;
    double A=1.0, Bv=0.0, C=0.0, Dv=1.0, ld2 = 0.0;
    for (int q = 0; q < NLAY; ++q) {
      int j = 0;
      for (int k = 1; k <= 15; ++k) j += (y >= Lb[q][k]) ? 1 : 0;
      const double* M = LM[q][j];
      ld2 += Ld[q][j];
      double A2 = M[0]*A + M[1]*C, B2 = M[0]*Bv + M[1]*Dv;
      double C2 = M[2]*A + M[3]*C, D2 = M[2]*Bv + M[3]*Dv;
      y = (M[0]*y + M[1]) / (M[2]*y + M[3]);
      A=A2; Bv=B2; C=C2; Dv=D2;
    }
    double sinv = exp2(-0.5 * ld2);              // det -> 1
    float4 c4;
    c4.x = (float)(A*sinv); c4.y = (float)(Bv*sinv);
    c4.z = (float)(C*sinv); c4.w = (float)(Dv*sinv);
    *(float4*)(F + OFF_CF0 + (size_t)(p*DIM + d)*4) = c4;
  }
}

template <int CTRL>
__device__ __forceinline__ float dpp_add(float x) {
  // bound_ctrl=true: invalid source lanes read 0 -> folds to one v_add_f32_dpp
  int yi = __builtin_amdgcn_update_dpp(0, __float_as_int(x), CTRL, 0xF, 0xF, true);
  return x + __int_as_float(yi);
}
// wave64 sum -> lane 63 (rocPRIM gfx9 sequence)
__device__ __forceinline__ float wave_sum63(float x) {
  x = dpp_add<0x111>(x);  // row_shr:1
  x = dpp_add<0x112>(x);  // row_shr:2
  x = dpp_add<0x114>(x);  // row_shr:4
  x = dpp_add<0x118>(x);  // row_shr:8
  x = dpp_add<0x142>(x);  // row_bcast:15
  x = dpp_add<0x143>(x);  // row_bcast:31
  return x;
}

// Main: lane = dim; wave owns 32 rows as 16 units of 2, software-pipelined:
//   R1: coarse(unit k+1) + issue fine-knot reads + X prefetch(unit k+2)
//   R2: math(unit k) with coeffs read LAST iteration (latency hidden)
//   R3: fine-search(unit k+1) + issue coeff reads
// 3 groups x (unroll 5) with group-local pointers: all global offsets <= 2304B
// fold into the load/store instructions.
__global__ __launch_bounds__(1024, 4) void nf_main(const float* __restrict__ X,
                                                   const float* __restrict__ F,
                                                   float* __restrict__ OUT,
                                                   float* __restrict__ LDo) {
  __shared__ float smem[19712];   // [0,4096): knots  [4096,19712): 61 coeff rows
  int t = threadIdx.x;
  {
    float4* dst = (float4*)smem;
    const float4* kt = (const float4*)(F + OFF_KN0);
    dst[t] = kt[t];
    const float4* ct = (const float4*)(F + OFF_CF0);
    for (int i = t; i < 3904; i += 1024) dst[1024 + i] = ct[i];
  }
  int d = t & 63;
  float k1 = F[OFF_CRS + 0*DIM + d];
  float k2 = F[OFF_CRS + 1*DIM + d];
  float k3 = F[OFF_CRS + 2*DIM + d];
  float k4 = F[OFF_CRS + 3*DIM + d];
  float k5 = F[OFF_CRS + 4*DIM + d];
  float k6 = F[OFF_CRS + 5*DIM + d];
  float k7 = F[OFF_CRS + 6*DIM + d];
  __syncthreads();
  const float4* skv = (const float4*)smem;

  int gw = blockIdx.x * 16 + (t >> 6);          // 0..8191; wave owns 32 rows
  const float* Xp = X   + (size_t)gw*32*DIM + d;
  float*       Op = OUT + (size_t)gw*32*DIM + d;
  float*       Lp = LDo + (size_t)gw*32;

#define COARSE(xc) ((xc>=k1)+(xc>=k2)+(xc>=k3)+(xc>=k4)+(xc>=k5)+(xc>=k6)+(xc>=k7))
#define FINE(xc, cc, f0, f1) \
  ((cc<<3) + (int)(xc>=f0.y)+(int)(xc>=f0.z)+(int)(xc>=f0.w)+(int)(xc>=f1.x) \
           + (int)(xc>=f1.y)+(int)(xc>=f1.z)+(int)(xc>=f1.w))

  // ---- prologue: full search of unit 0; load x of unit 1 ----
  float xA0 = Xp[0], xA1 = Xp[64];
  float xB0 = Xp[128], xB1 = Xp[192];
  float xcA0 = __builtin_amdgcn_fmed3f(xA0, -3.f, 3.f);
  float xcA1 = __builtin_amdgcn_fmed3f(xA1, -3.f, 3.f);
  float4 cfA0, cfA1;
  {
    int c0 = COARSE(xcA0), c1 = COARSE(xcA1);
    float4 f00 = skv[(c0<<6)+d], f01 = skv[512+(c0<<6)+d];
    float4 f10 = skv[(c1<<6)+d], f11 = skv[512+(c1<<6)+d];
    int p0 = FINE(xcA0, c0, f00, f01);
    int p1 = FINE(xcA1, c1, f10, f11);
    cfA0 = skv[1024+(p0<<6)+d];
    cfA1 = skv[1024+(p1<<6)+d];
  }

  for (int g = 0; g < 3; ++g) {
#pragma unroll
    for (int u = 0; u < 5; ++u) {
      // ---- R1: coarse(next unit), issue fine reads; prefetch x(unit+2) ----
      float xcB0 = __builtin_amdgcn_fmed3f(xB0, -3.f, 3.f);
      float xcB1 = __builtin_amdgcn_fmed3f(xB1, -3.f, 3.f);
      int cB0 = COARSE(xcB0), cB1 = COARSE(xcB1);
      float4 f00 = skv[(cB0<<6)+d], f01 = skv[512+(cB0<<6)+d];
      float4 f10 = skv[(cB1<<6)+d], f11 = skv[512+(cB1<<6)+d];
      int lo = (u == 4) ? ((g == 2) ? 5 : 6) : (u + 2);   // group-local prefetch unit
      float xF0 = Xp[lo*128], xF1 = Xp[lo*128 + 64];
      __builtin_amdgcn_sched_barrier(0);
      // ---- R2: math(unit g*5+u) using cfA (read last iteration) ----
      float num0 = fmaf(cfA0.x, xcA0, cfA0.y);
      float den0 = fmaf(cfA0.z, xcA0, cfA0.w);
      float o0 = (xA0 == xcA0) ? __fdividef(num0, den0) : xA0;
      float l0 = __log2f(fabsf(den0));
      float num1 = fmaf(cfA1.x, xcA1, cfA1.y);
      float den1 = fmaf(cfA1.z, xcA1, cfA1.w);
      float o1 = (xA1 == xcA1) ? __fdividef(num1, den1) : xA1;
      float l1 = __log2f(fabsf(den1));
      Op[u*128] = o0; Op[u*128 + 64] = o1;
      float s0 = wave_sum63(l0);
      float s1 = wave_sum63(l1);
      if (d == 63) {
        float2 v;
        v.x = s0 * -1.3862943611198906f;   // -2*ln2 folded once per row
        v.y = s1 * -1.3862943611198906f;
        *(float2*)(Lp + 2*u) = v;
      }
      __builtin_amdgcn_sched_barrier(0);
      // ---- R3: fine-search(next unit) + issue coeff reads ----
      int p0 = FINE(xcB0, cB0, f00, f01);
      int p1 = FINE(xcB1, cB1, f10, f11);
      cfA0 = skv[1024+(p0<<6)+d];
      cfA1 = skv[1024+(p1<<6)+d];
      xA0 = xB0; xA1 = xB1; xcA0 = xcB0; xcA1 = xcB1;
      xB0 = xF0; xB1 = xF1;
    }
    Xp += 640; Op += 640; Lp += 10;
  }
  // ---- epilogue: math(unit 15); Op/Lp now point at its slots ----
  {
    float num0 = fmaf(cfA0.x, xcA0, cfA0.y);
    float den0 = fmaf(cfA0.z, xcA0, cfA0.w);
    float o0 = (xA0 == xcA0) ? __fdividef(num0, den0) : xA0;
    float l0 = __log2f(fabsf(den0));
    float num1 = fmaf(cfA1.x, xcA1, cfA1.y);
    float den1 = fmaf(cfA1.z, xcA1, cfA1.w);
    float o1 = (xA1 == xcA1) ? __fdividef(num1, den1) : xA1;
    float l1 = __log2f(fabsf(den1));
    Op[0] = o0; Op[64] = o1;
    float s0 = wave_sum63(l0);
    float s1 = wave_sum63(l1);
    if (d == 63) {
      float2 v;
      v.x = s0 * -1.3862943611198906f;
      v.y = s1 * -1.3862943611198906f;
      *(float2*)Lp = v;
    }
  }
#undef COARSE
#undef FINE
}

extern "C" void kernel_launch(void* const* d_in, const int* in_sizes, int n_in,
                              void* d_out, int out_size, void* d_ws, size_t ws_size,
                              hipStream_t stream) {
  const float* x  = (const float*)d_in[0];
  const float* uw = (const float*)d_in[1];
  const float* uh = (const float*)d_in[2];
  const float* ud = (const float*)d_in[3];
  const float* ul = (const float*)d_in[4];
  float* out = (float*)d_out;
  float* F = (float*)d_ws;
  nf_pre<<<DIM, 64, 0, stream>>>(uw, uh, ud, ul, F);
  nf_main<<<512, 1024, 0, stream>>>(x, F, out, out + (size_t)BATCH*DIM);
}